// Round 4
// baseline (663.877 us; speedup 1.0000x reference)
//
#include <hip/hip_runtime.h>
#include <hip/hip_bf16.h>

#define Bsz 4
#define SQ 4096
#define SK 4096
#define DMODEL 1024
#define DKk 64
#define QBLKS 16   // SQ/256 q-blocks in k_score (partial colsum splits)
#define SSPL 4     // s-splits in k_pv

typedef __attribute__((ext_vector_type(8))) short bf8_t;
typedef __attribute__((ext_vector_type(4))) float f4_t;

#define MFMA(a, b, c) __builtin_amdgcn_mfma_f32_16x16x32_bf16((a), (b), (c), 0, 0, 0)

// Workspace byte offsets (ws = 1 GiB per harness fill evidence). Total ~137.1 MiB.
#define OFF_Q    ((size_t)0)              // bf16 [B*SQ][64]    2 MiB  (prescaled by 1/8)
#define OFF_K    ((size_t)(2u   << 20))   // bf16 [B*SK][64]    2 MiB
#define OFF_V    ((size_t)(4u   << 20))   // bf16 [B*SK][64]    2 MiB
#define OFF_VT   ((size_t)(6u   << 20))   // bf16 [B][64][SK]   2 MiB  (V*linv, transposed)
#define OFF_P    ((size_t)(8u   << 20))   // bf16 [B][SQ][SK] 128 MiB  (masked exp scores)
#define OFF_PART ((size_t)(136u << 20))   // f32  [QBLKS][B][SK] 1 MiB
#define OFF_LINV ((size_t)(137u << 20))   // f32  [B][SK]      64 KiB

__device__ __forceinline__ short f2bf(float f) {
    union { float f; unsigned u; } v; v.f = f;
    return (short)((v.u + 0x7FFFu + ((v.u >> 16) & 1u)) >> 16);
}
__device__ __forceinline__ float bf2f(short h) {
    union { unsigned u; float f; } v; v.u = ((unsigned)(unsigned short)h) << 16;
    return v.f;
}
__device__ __forceinline__ bf8_t cvt8(float4 a, float4 b) {
    union { __hip_bfloat162 h[4]; bf8_t v; } u;
    u.h[0] = __float22bfloat162_rn(float2{a.x, a.y});
    u.h[1] = __float22bfloat162_rn(float2{a.z, a.w});
    u.h[2] = __float22bfloat162_rn(float2{b.x, b.y});
    u.h[3] = __float22bfloat162_rn(float2{b.z, b.w});
    return u.v;
}

// K0: zero d_out (poisoned 0xAA; k_pv accumulates via atomics). 1M floats.
__global__ void k_zero(float4* __restrict__ out)
{
    out[blockIdx.x * 256 + threadIdx.x] = float4{0.f, 0.f, 0.f, 0.f};
}

// ---------------------------------------------------------------------------
// K1: QKV projection via MFMA (unchanged from round 3 — passed).
// out = bf16((x @ W^T + b) * scale), Q prescaled by 1/8.
// ---------------------------------------------------------------------------
__global__ __launch_bounds__(256) void k_proj(
    const float* __restrict__ xq, const float* __restrict__ xk, const float* __restrict__ xv,
    const float* __restrict__ Wq, const float* __restrict__ bq,
    const float* __restrict__ Wk, const float* __restrict__ bk,
    const float* __restrict__ Wv, const float* __restrict__ bv,
    char* __restrict__ ws)
{
    const int t = threadIdx.x, l = t & 63, w = t >> 6;
    const int l15 = l & 15, g = l >> 4;
    const int which = blockIdx.y;
    const float* x    = which == 0 ? xq : (which == 1 ? xk : xv);
    const float* W    = which == 0 ? Wq : (which == 1 ? Wk : Wv);
    const float* bias = which == 0 ? bq : (which == 1 ? bk : bv);
    short* out = (short*)(ws + (which == 0 ? OFF_Q : (which == 1 ? OFF_K : OFF_V)));
    const float scale = (which == 0) ? 0.125f : 1.0f;

    const int row0 = blockIdx.x * 128 + w * 32;

    f4_t acc[2][4];
#pragma unroll
    for (int m = 0; m < 2; ++m)
#pragma unroll
        for (int n = 0; n < 4; ++n) acc[m][n] = f4_t{0.f, 0.f, 0.f, 0.f};

    for (int kc = 0; kc < DMODEL; kc += 32) {
        bf8_t af[2], bfg[4];
#pragma unroll
        for (int m = 0; m < 2; ++m) {
            const float* p = x + (size_t)(row0 + m * 16 + l15) * DMODEL + kc + g * 8;
            af[m] = cvt8(*(const float4*)p, *(const float4*)(p + 4));
        }
#pragma unroll
        for (int n = 0; n < 4; ++n) {
            const float* p = W + (size_t)(n * 16 + l15) * DMODEL + kc + g * 8;
            bfg[n] = cvt8(*(const float4*)p, *(const float4*)(p + 4));
        }
#pragma unroll
        for (int m = 0; m < 2; ++m)
#pragma unroll
            for (int n = 0; n < 4; ++n) acc[m][n] = MFMA(af[m], bfg[n], acc[m][n]);
    }

#pragma unroll
    for (int n = 0; n < 4; ++n) {
        const float bb = bias[n * 16 + l15];
#pragma unroll
        for (int m = 0; m < 2; ++m)
#pragma unroll
            for (int i = 0; i < 4; ++i) {
                const int row = row0 + m * 16 + g * 4 + i;
                out[(size_t)row * DKk + n * 16 + l15] = f2bf((acc[m][n][i] + bb) * scale);
            }
    }
}

// ---------------------------------------------------------------------------
// K2: score pass. Computes S^T-fragments (A=K rows=s, B=Q cols=q), applies
// mask (direct int4 read: 4 consecutive s per lane), exp -> P bf16 stored
// row-major [q][s] as packed 8-B writes; accumulates per-s column partial
// sums, reduced across the 16 q-lanes + 4 waves -> part[qblk][b][s].
// Block: 64 s x 256 q (wave w owns q-range w*64). grid (SK/64, SQ/256, B).
// ---------------------------------------------------------------------------
__global__ __launch_bounds__(256) void k_score(
    const short* __restrict__ Q, const short* __restrict__ K,
    const int* __restrict__ mask, short* __restrict__ P, float* __restrict__ part)
{
    __shared__ float red[4][64];
    const int t = threadIdx.x, l = t & 63, w = t >> 6;
    const int l15 = l & 15, g = l >> 4;
    const int s0 = blockIdx.x * 64;
    const int b  = blockIdx.z;
    const int q0 = blockIdx.y * 256 + w * 64;

    bf8_t ka[4][2];
#pragma unroll
    for (int m = 0; m < 4; ++m)
#pragma unroll
        for (int ks = 0; ks < 2; ++ks)
            ka[m][ks] = *(const bf8_t*)(K + ((size_t)b * SK + s0 + m * 16 + l15) * DKk + ks * 32 + g * 8);

    float cs[4][4];
#pragma unroll
    for (int m = 0; m < 4; ++m)
#pragma unroll
        for (int i = 0; i < 4; ++i) cs[m][i] = 0.f;

#pragma unroll
    for (int n = 0; n < 4; ++n) {
        const size_t qrow = (size_t)b * SQ + q0 + n * 16 + l15;
        const bf8_t qb0 = *(const bf8_t*)(Q + qrow * DKk + g * 8);
        const bf8_t qb1 = *(const bf8_t*)(Q + qrow * DKk + 32 + g * 8);
#pragma unroll
        for (int m = 0; m < 4; ++m) {
            f4_t a = {0.f, 0.f, 0.f, 0.f};
            a = MFMA(ka[m][0], qb0, a);
            a = MFMA(ka[m][1], qb1, a);
            const int soff = s0 + m * 16 + g * 4;
            const int4 mk = *(const int4*)(mask + qrow * SK + soff);
            const float p0 = mk.x ? __expf(a[0]) : 0.f;
            const float p1 = mk.y ? __expf(a[1]) : 0.f;
            const float p2 = mk.z ? __expf(a[2]) : 0.f;
            const float p3 = mk.w ? __expf(a[3]) : 0.f;
            cs[m][0] += p0; cs[m][1] += p1; cs[m][2] += p2; cs[m][3] += p3;
            union { __hip_bfloat162 h[2]; uint2 u2; } pk;
            pk.h[0] = __float22bfloat162_rn(float2{p0, p1});
            pk.h[1] = __float22bfloat162_rn(float2{p2, p3});
            *(uint2*)(P + qrow * SK + soff) = pk.u2;
        }
    }

    // reduce colsum partials across the 16 q-lanes (l15)
#pragma unroll
    for (int m = 0; m < 4; ++m)
#pragma unroll
        for (int i = 0; i < 4; ++i) {
            float v = cs[m][i];
            v += __shfl_xor(v, 1); v += __shfl_xor(v, 2);
            v += __shfl_xor(v, 4); v += __shfl_xor(v, 8);
            cs[m][i] = v;
        }
    if (l15 == 0) {
#pragma unroll
        for (int m = 0; m < 4; ++m)
#pragma unroll
            for (int i = 0; i < 4; ++i) red[w][m * 16 + g * 4 + i] = cs[m][i];
    }
    __syncthreads();
    if (t < 64) {
        part[((size_t)blockIdx.y * Bsz + b) * SK + s0 + t] =
            red[0][t] + red[1][t] + red[2][t] + red[3][t];
    }
}

// K3: linv[b][s] = 1 / sum_j part[j][b][s].  grid (B*SK/256)
__global__ void k_linv(const float* __restrict__ part, float* __restrict__ linv)
{
    const int i = blockIdx.x * 256 + threadIdx.x;
    const int b = i >> 12, s = i & (SK - 1);
    float acc = 0.f;
#pragma unroll
    for (int j = 0; j < QBLKS; ++j) acc += part[((size_t)j * Bsz + b) * SK + s];
    linv[i] = 1.0f / acc;
}

// K4: Vt[b][k][s] = bf16(V[b][s][k] * linv[b][s]).  grid (B*SK*8/256)
__global__ void k_vscale(const short* __restrict__ V, const float* __restrict__ linv,
                         short* __restrict__ Vt)
{
    const int tg = blockIdx.x * 256 + threadIdx.x;   // 131072 threads
    const int b = tg >> 15, rem = tg & 32767;
    const int nch = rem >> 12, s = rem & 4095;
    const float li = linv[b * SK + s];
    union { short s[8]; bf8_t v; } u;
    u.v = *(const bf8_t*)(V + (size_t)(b * SK + s) * DKk + nch * 8);
#pragma unroll
    for (int j = 0; j < 8; ++j)
        Vt[(size_t)(b * DKk + nch * 8 + j) * SK + s] = f2bf(bf2f(u.s[j]) * li);
}

// ---------------------------------------------------------------------------
// K5: PV GEMM. y[q][k] += sum_s P[q][s] * Vt[k][s] over this block's s-range.
// Block: 128 q x 64 k, 4 waves (wave w: q-sub w*32, 2x4 fragments), s-split
// SSPL=4 via blockIdx.y, f32 atomicAdd into zeroed out. grid (SQ/128, 4, B).
// ---------------------------------------------------------------------------
__global__ __launch_bounds__(256) void k_pv(
    const short* __restrict__ P, const short* __restrict__ Vt, float* __restrict__ out)
{
    const int t = threadIdx.x, l = t & 63, w = t >> 6;
    const int l15 = l & 15, g = l >> 4;
    const int b = blockIdx.z;
    const int qbase = blockIdx.x * 128 + w * 32;
    const int sbase = blockIdx.y * (SK / SSPL);

    const short* Pb = P + (size_t)b * SQ * SK;
    const short* Vb = Vt + (size_t)b * DKk * SK;

    f4_t acc[2][4];
#pragma unroll
    for (int m = 0; m < 2; ++m)
#pragma unroll
        for (int n = 0; n < 4; ++n) acc[m][n] = f4_t{0.f, 0.f, 0.f, 0.f};

#pragma unroll 2
    for (int it = 0; it < (SK / SSPL) / 32; ++it) {
        const int s = sbase + it * 32 + g * 8;
        bf8_t pa[2], vb[4];
#pragma unroll
        for (int m = 0; m < 2; ++m)
            pa[m] = *(const bf8_t*)(Pb + (size_t)(qbase + m * 16 + l15) * SK + s);
#pragma unroll
        for (int n = 0; n < 4; ++n)
            vb[n] = *(const bf8_t*)(Vb + (size_t)(n * 16 + l15) * SK + s);
#pragma unroll
        for (int m = 0; m < 2; ++m)
#pragma unroll
            for (int n = 0; n < 4; ++n) acc[m][n] = MFMA(pa[m], vb[n], acc[m][n]);
    }

#pragma unroll
    for (int m = 0; m < 2; ++m)
#pragma unroll
        for (int n = 0; n < 4; ++n)
#pragma unroll
            for (int i = 0; i < 4; ++i)
                atomicAdd(out + ((size_t)b * SQ + qbase + m * 16 + g * 4 + i) * DKk + n * 16 + l15,
                          acc[m][n][i]);
}

// ---------------------------------------------------------------------------
extern "C" void kernel_launch(void* const* d_in, const int* in_sizes, int n_in,
                              void* d_out, int out_size, void* d_ws, size_t ws_size,
                              hipStream_t stream)
{
    (void)in_sizes; (void)n_in; (void)out_size; (void)ws_size;
    const float* xq = (const float*)d_in[0];
    const float* xk = (const float*)d_in[1];
    const float* xv = (const float*)d_in[2];
    const int*  mask = (const int*)d_in[3];
    const float* Wq = (const float*)d_in[4];
    const float* bq = (const float*)d_in[5];
    const float* Wk = (const float*)d_in[6];
    const float* bk = (const float*)d_in[7];
    const float* Wv = (const float*)d_in[8];
    const float* bv = (const float*)d_in[9];
    float* out = (float*)d_out;
    char* ws = (char*)d_ws;

    short* Q    = (short*)(ws + OFF_Q);
    short* Kk   = (short*)(ws + OFF_K);
    short* V    = (short*)(ws + OFF_V);
    short* Vt   = (short*)(ws + OFF_VT);
    short* P    = (short*)(ws + OFF_P);
    float* part = (float*)(ws + OFF_PART);
    float* linv = (float*)(ws + OFF_LINV);

    k_zero<<<dim3((Bsz * SQ * DKk / 4) / 256), dim3(256), 0, stream>>>((float4*)out);
    k_proj<<<dim3(128, 3), dim3(256), 0, stream>>>(xq, xk, xv, Wq, bq, Wk, bk, Wv, bv, ws);
    k_score<<<dim3(SK / 64, SQ / 256, Bsz), dim3(256), 0, stream>>>(Q, Kk, mask, P, part);
    k_linv<<<dim3((Bsz * SK) / 256), dim3(256), 0, stream>>>(part, linv);
    k_vscale<<<dim3((Bsz * SK * 8) / 256), dim3(256), 0, stream>>>(V, linv, Vt);
    k_pv<<<dim3(SQ / 128, SSPL, Bsz), dim3(256), 0, stream>>>(P, Vt, out);
}